// Round 5
// baseline (3614.653 us; speedup 1.0000x reference)
//
#include <hip/hip_runtime.h>

// out[b,c,y,x] = sum_{kdy,kdx in [0,9)} corr[b, kdy*9+kdx, y+4-kdy, x+4-kdx] * feat[b,c, y+4-kdy, x+4-kdx]
// (zero padding outside [0,96) in both spatial dims)

#define RR 4
#define DD 9
#define D2 81
#define Bn 16
#define Cn 256
#define Hn 96
#define Wn 96
#define HWn (Hn*Wn)

#define NTX 12            // x-lane groups
#define TXR 8             // x outputs per thread
#define NTC 32            // channel lanes
#define CT  2             // channels per thread
#define NCB (NTC*CT)      // 64 channels per block
#define NCG (Cn/NCB)      // 4 channel groups
#define NTH (NTX*NTC)     // 384 threads
#define LW  104           // padded LDS row width (floats)
#define LW4 (LW/4)        // 26 float4 per row

__global__ __launch_bounds__(NTH, 4)
void corrT5_kernel(const float* __restrict__ corr,
                   const float* __restrict__ feat,
                   float* __restrict__ out)
{
    __shared__ float lds[D2 * LW];          // 81*104*4 = 33696 B

    // XCD-chunked bijective swizzle (grid 6144 % 8 == 0)
    int bid = blockIdx.x;
    int sw  = (bid & 7) * (gridDim.x >> 3) + (bid >> 3);
    int cg  = sw & (NCG - 1);               // channel-group fastest: corr L2 reuse
    int y   = (sw >> 2) % Hn;
    int b   = sw / (NCG * Hn);

    const int tid = threadIdx.x;
    const float* corrb = corr + (size_t)b * D2 * HWn;

    // ---- stage corr rows into LDS, x-shifted by kdx, zero-padded ----
    // lds[row][col] = corr[b, row, y+4-kdy, col - kdx]  (0 if OOB), row = kdy*9+kdx
    for (int idx = tid; idx < D2 * LW4; idx += NTH) {
        int row = idx / LW4;
        int c4  = idx - row * LW4;
        int kdy = row / DD;
        int kdx = row - kdy * DD;
        int sy  = y + RR - kdy;
        float4 v = make_float4(0.f, 0.f, 0.f, 0.f);
        if (sy >= 0 && sy < Hn) {
            const float* src = corrb + (size_t)row * HWn + sy * Wn;
            int col0 = c4 * 4;
            #pragma unroll
            for (int e = 0; e < 4; ++e) {
                int sx = col0 + e - kdx;
                if (sx >= 0 && sx < Wn) (&v.x)[e] = src[sx];
            }
        }
        *reinterpret_cast<float4*>(&lds[row * LW + c4 * 4]) = v;
    }
    __syncthreads();

    const int tx = tid % NTX;
    const int tc = tid / NTX;
    const int x0 = tx * TXR;
    const int c0 = cg * NCB + tc * CT;

    const float* featb = feat + ((size_t)b * Cn + c0) * HWn;
    const float4* cvp  = reinterpret_cast<const float4*>(lds) + (tx * 2 + 1);

    float acc[CT][TXR] = {};

    // one kdy step: 8 global float4 + 18 LDS b128 + 144 FMA, all-static indices
#define KDY_BODY(kdy)                                                                     \
    {                                                                                     \
        const int sy = y + RR - (kdy);                                                    \
        float f[CT][16];                                                                  \
        const float* frow = featb + sy * Wn + x0 - RR;                                    \
        _Pragma("unroll")                                                                 \
        for (int c = 0; c < CT; ++c) {                                                    \
            const float* p = frow + (size_t)c * HWn;                                      \
            float4 f0 = (tx == 0)       ? make_float4(0,0,0,0) : *reinterpret_cast<const float4*>(p);      \
            float4 f1 = *reinterpret_cast<const float4*>(p + 4);                          \
            float4 f2 = *reinterpret_cast<const float4*>(p + 8);                          \
            float4 f3 = (tx == NTX - 1) ? make_float4(0,0,0,0) : *reinterpret_cast<const float4*>(p + 12); \
            f[c][0]=f0.x;  f[c][1]=f0.y;  f[c][2]=f0.z;  f[c][3]=f0.w;                    \
            f[c][4]=f1.x;  f[c][5]=f1.y;  f[c][6]=f1.z;  f[c][7]=f1.w;                    \
            f[c][8]=f2.x;  f[c][9]=f2.y;  f[c][10]=f2.z; f[c][11]=f2.w;                   \
            f[c][12]=f3.x; f[c][13]=f3.y; f[c][14]=f3.z; f[c][15]=f3.w;                   \
        }                                                                                 \
        _Pragma("unroll")                                                                 \
        for (int kdx = 0; kdx < DD; ++kdx) {                                              \
            int row = (kdy) * DD + kdx;                                                   \
            float4 ca = cvp[row * LW4];                                                   \
            float4 cb = cvp[row * LW4 + 1];                                               \
            float cv[8] = {ca.x, ca.y, ca.z, ca.w, cb.x, cb.y, cb.z, cb.w};               \
            _Pragma("unroll")                                                             \
            for (int c = 0; c < CT; ++c)                                                  \
                _Pragma("unroll")                                                         \
                for (int j = 0; j < TXR; ++j)                                             \
                    acc[c][j] = fmaf(cv[j], f[c][j + 8 - kdx], acc[c][j]);                \
        }                                                                                 \
    }

    if (y >= RR && y <= Hn - 1 - RR) {
        // interior: full compile-time 9-iteration unroll -> compiler software-pipelines
        #pragma unroll
        for (int kdy = 0; kdy < DD; ++kdy)
            KDY_BODY(kdy)
    } else {
        // border: runtime-bounded loop (8 of 96 y values)
        const int klo = max(0, y - (Hn - 1 - RR));
        const int khi = min(DD - 1, y + RR);
        #pragma unroll 1
        for (int kdy = klo; kdy <= khi; ++kdy)
            KDY_BODY(kdy)
    }
#undef KDY_BODY

    float* ob = out + ((size_t)b * Cn + c0) * HWn + (size_t)y * Wn + x0;
    #pragma unroll
    for (int c = 0; c < CT; ++c) {
        *reinterpret_cast<float4*>(ob + (size_t)c * HWn)     = make_float4(acc[c][0], acc[c][1], acc[c][2], acc[c][3]);
        *reinterpret_cast<float4*>(ob + (size_t)c * HWn + 4) = make_float4(acc[c][4], acc[c][5], acc[c][6], acc[c][7]);
    }
}

extern "C" void kernel_launch(void* const* d_in, const int* in_sizes, int n_in,
                              void* d_out, int out_size, void* d_ws, size_t ws_size,
                              hipStream_t stream)
{
    const float* corr = (const float*)d_in[0];   // [16,81,96,96]
    const float* feat = (const float*)d_in[1];   // [16,256,96,96]
    float* out = (float*)d_out;                  // [16,256,96,96]

    const int grid = Bn * Hn * NCG;              // 16*96*4 = 6144
    corrT5_kernel<<<grid, NTH, 0, stream>>>(corr, feat, out);
}

// Round 6
// 2072.794 us; speedup vs baseline: 1.7439x; 1.7439x over previous
//
#include <hip/hip_runtime.h>

// out[b,c,y,x] = sum_{kdy,kdx in [0,9)} corr[b, kdy*9+kdx, y+4-kdy, x+4-kdx] * feat[b,c, y+4-kdy, x+4-kdx]
// (zero padding outside [0,96) in both spatial dims)

#define RR 4
#define DD 9
#define D2 81
#define Bn 16
#define Cn 256
#define Hn 96
#define Wn 96
#define HWn (Hn*Wn)

#define NTX 12            // x-lane groups
#define TXR 8             // x outputs per thread
#define NTC 32            // channel lanes
#define CT  2             // channels per thread
#define NCB (NTC*CT)      // 64 channels per block
#define NCG (Cn/NCB)      // 4 channel groups
#define NTH (NTX*NTC)     // 384 threads
#define LW  104           // padded LDS row width (floats)
#define LW4 (LW/4)        // 26 float4 per row

__global__ __launch_bounds__(NTH, 4)
void corrT6_kernel(const float* __restrict__ corr,
                   const float* __restrict__ feat,
                   float* __restrict__ out)
{
    __shared__ float lds[D2 * LW];          // 81*104*4 = 33696 B

    // XCD-chunked bijective swizzle (grid 6144 % 8 == 0)
    int bid = blockIdx.x;
    int sw  = (bid & 7) * (gridDim.x >> 3) + (bid >> 3);
    int cg  = sw & (NCG - 1);               // channel-group fastest: corr L2 reuse
    int y   = (sw >> 2) % Hn;
    int b   = sw / (NCG * Hn);

    const int tid = threadIdx.x;
    const float* corrb = corr + (size_t)b * D2 * HWn;

    // ---- stage corr rows into LDS, x-shifted by kdx, zero-padded ----
    // lds[row][col] = corr[b, row, y+4-kdy, col - kdx]  (0 if OOB), row = kdy*9+kdx
    for (int idx = tid; idx < D2 * LW4; idx += NTH) {
        int row = idx / LW4;
        int c4  = idx - row * LW4;
        int kdy = row / DD;
        int kdx = row - kdy * DD;
        int sy  = y + RR - kdy;
        float4 v = make_float4(0.f, 0.f, 0.f, 0.f);
        if (sy >= 0 && sy < Hn) {
            const float* src = corrb + (size_t)row * HWn + sy * Wn;
            int col0 = c4 * 4;
            #pragma unroll
            for (int e = 0; e < 4; ++e) {
                int sx = col0 + e - kdx;
                if (sx >= 0 && sx < Wn) (&v.x)[e] = src[sx];
            }
        }
        *reinterpret_cast<float4*>(&lds[row * LW + c4 * 4]) = v;
    }
    __syncthreads();

    const int tx = tid % NTX;
    const int tc = tid / NTX;
    const int x0 = tx * TXR;
    const int c0 = cg * NCB + tc * CT;

    const float* featb = feat + ((size_t)b * Cn + c0) * HWn;
    const float4* cvp  = reinterpret_cast<const float4*>(lds) + (tx * 2 + 1);
    const float4 z4    = make_float4(0.f, 0.f, 0.f, 0.f);

    float acc[CT][TXR] = {};

    // contiguous valid kdy range: sy = y+4-kdy in [0,96)
    const int klo = max(0, y - (Hn - 1 - RR));
    const int khi = min(DD - 1, y + RR);

    // named-register feat window buffers (NO arrays across statements -> no scratch)
    float4 cA0, cA1, cA2, cA3, cB0, cB1, cB2, cB3;   // current
    float4 nA0, nA1, nA2, nA3, nB0, nB1, nB2, nB3;   // next (prefetch)

// load feat window for source row (syv) into buffer P: P?0..P?3, ch A/B
#define LOADF(P, syv)                                                                     \
    {                                                                                     \
        const float* p0 = featb + (syv) * Wn + x0 - RR;                                   \
        const float* p1 = p0 + HWn;                                                       \
        P##A0 = (tx == 0)       ? z4 : *reinterpret_cast<const float4*>(p0);              \
        P##A1 = *reinterpret_cast<const float4*>(p0 + 4);                                 \
        P##A2 = *reinterpret_cast<const float4*>(p0 + 8);                                 \
        P##A3 = (tx == NTX - 1) ? z4 : *reinterpret_cast<const float4*>(p0 + 12);         \
        P##B0 = (tx == 0)       ? z4 : *reinterpret_cast<const float4*>(p1);              \
        P##B1 = *reinterpret_cast<const float4*>(p1 + 4);                                 \
        P##B2 = *reinterpret_cast<const float4*>(p1 + 8);                                 \
        P##B3 = (tx == NTX - 1) ? z4 : *reinterpret_cast<const float4*>(p1 + 12);         \
    }

// consume one kdy from buffer P: 18 LDS b128 + 144 FMA (f[] is local, static-indexed)
#define COMPUTE(P, kdyv)                                                                  \
    {                                                                                     \
        float f[CT][16] = {                                                               \
            {P##A0.x, P##A0.y, P##A0.z, P##A0.w, P##A1.x, P##A1.y, P##A1.z, P##A1.w,      \
             P##A2.x, P##A2.y, P##A2.z, P##A2.w, P##A3.x, P##A3.y, P##A3.z, P##A3.w},     \
            {P##B0.x, P##B0.y, P##B0.z, P##B0.w, P##B1.x, P##B1.y, P##B1.z, P##B1.w,      \
             P##B2.x, P##B2.y, P##B2.z, P##B2.w, P##B3.x, P##B3.y, P##B3.z, P##B3.w}};    \
        _Pragma("unroll")                                                                 \
        for (int kdx = 0; kdx < DD; ++kdx) {                                              \
            int row = (kdyv) * DD + kdx;                                                  \
            float4 ca = cvp[row * LW4];                                                   \
            float4 cb = cvp[row * LW4 + 1];                                               \
            float cv[8] = {ca.x, ca.y, ca.z, ca.w, cb.x, cb.y, cb.z, cb.w};               \
            _Pragma("unroll")                                                             \
            for (int c = 0; c < CT; ++c)                                                  \
                _Pragma("unroll")                                                         \
                for (int j = 0; j < TXR; ++j)                                             \
                    acc[c][j] = fmaf(cv[j], f[c][j + 8 - kdx], acc[c][j]);                \
        }                                                                                 \
    }

    // depth-1 software pipeline, ping-pong on named register sets, no copies
    LOADF(c, y + RR - klo)
    int kdy = klo;
    #pragma unroll 1
    for (; kdy + 2 <= khi; kdy += 2) {
        LOADF(n, y + RR - (kdy + 1))     // in flight under COMPUTE(c)
        COMPUTE(c, kdy)
        LOADF(c, y + RR - (kdy + 2))     // in flight under COMPUTE(n)
        COMPUTE(n, kdy + 1)
    }
    if (kdy + 1 <= khi) {
        LOADF(n, y + RR - (kdy + 1))
        COMPUTE(c, kdy)
        COMPUTE(n, kdy + 1)
    } else {
        COMPUTE(c, kdy)
    }
#undef LOADF
#undef COMPUTE

    float* ob = out + ((size_t)b * Cn + c0) * HWn + (size_t)y * Wn + x0;
    #pragma unroll
    for (int c = 0; c < CT; ++c) {
        *reinterpret_cast<float4*>(ob + (size_t)c * HWn)     = make_float4(acc[c][0], acc[c][1], acc[c][2], acc[c][3]);
        *reinterpret_cast<float4*>(ob + (size_t)c * HWn + 4) = make_float4(acc[c][4], acc[c][5], acc[c][6], acc[c][7]);
    }
}

extern "C" void kernel_launch(void* const* d_in, const int* in_sizes, int n_in,
                              void* d_out, int out_size, void* d_ws, size_t ws_size,
                              hipStream_t stream)
{
    const float* corr = (const float*)d_in[0];   // [16,81,96,96]
    const float* feat = (const float*)d_in[1];   // [16,256,96,96]
    float* out = (float*)d_out;                  // [16,256,96,96]

    const int grid = Bn * Hn * NCG;              // 16*96*4 = 6144
    corrT6_kernel<<<grid, NTH, 0, stream>>>(corr, feat, out);
}

// Round 7
// 254.689 us; speedup vs baseline: 14.1924x; 8.1385x over previous
//
#include <hip/hip_runtime.h>

// out[b,c,y,x] = sum_{kdy,kdx in [0,9)} corr[b, kdy*9+kdx, y+4-kdy, x+4-kdx] * feat[b,c, y+4-kdy, x+4-kdx]
// (zero padding outside [0,96) in both spatial dims)

#define RR 4
#define DD 9
#define D2 81
#define Bn 16
#define Cn 256
#define Hn 96
#define Wn 96
#define HWn (Hn*Wn)

#define NTX 12            // x-lane groups
#define TXR 8             // x outputs per thread
#define NTC 32            // channel lanes
#define CT  2             // channels per thread
#define NCB (NTC*CT)      // 64 channels per block
#define NCG (Cn/NCB)      // 4 channel groups
#define NTH (NTX*NTC)     // 384 threads
#define LW  104           // padded LDS row width (floats)
#define LW4 (LW/4)        // 26 float4 per row

__global__ __launch_bounds__(NTH, 6)
void corrT7_kernel(const float* __restrict__ corr,
                   const float* __restrict__ feat,
                   float* __restrict__ out)
{
    __shared__ float lds[D2 * LW];          // 81*104*4 = 33696 B

    // XCD-chunked bijective swizzle (grid 6144 % 8 == 0)
    int bid = blockIdx.x;
    int sw  = (bid & 7) * (gridDim.x >> 3) + (bid >> 3);
    int cg  = sw & (NCG - 1);               // channel-group fastest: corr L2 reuse
    int y   = (sw >> 2) % Hn;
    int b   = sw / (NCG * Hn);

    const int tid = threadIdx.x;
    const float* corrb = corr + (size_t)b * D2 * HWn;

    // ---- stage corr rows into LDS, x-shifted by kdx, zero-padded ----
    // lds[row][col] = corr[b, row, y+4-kdy, col - kdx]  (0 if OOB), row = kdy*9+kdx
    for (int idx = tid; idx < D2 * LW4; idx += NTH) {
        int row = idx / LW4;
        int c4  = idx - row * LW4;
        int kdy = row / DD;
        int kdx = row - kdy * DD;
        int sy  = y + RR - kdy;
        float4 v = make_float4(0.f, 0.f, 0.f, 0.f);
        if (sy >= 0 && sy < Hn) {
            const float* src = corrb + (size_t)row * HWn + sy * Wn;
            int col0 = c4 * 4;
            #pragma unroll
            for (int e = 0; e < 4; ++e) {
                int sx = col0 + e - kdx;
                if (sx >= 0 && sx < Wn) (&v.x)[e] = src[sx];
            }
        }
        *reinterpret_cast<float4*>(&lds[row * LW + c4 * 4]) = v;
    }
    __syncthreads();

    const int tx = tid % NTX;
    const int tc = tid / NTX;
    const int x0 = tx * TXR;
    const int c0 = cg * NCB + tc * CT;

    const float* featb = feat + ((size_t)b * Cn + c0) * HWn;

    float acc[CT][TXR] = {};

    // contiguous valid kdy range: sy = y+4-kdy in [0,96)
    const int klo = max(0, y - (Hn - 1 - RR));
    const int khi = min(DD - 1, y + RR);

    #pragma unroll 1
    for (int kdy = klo; kdy <= khi; ++kdy) {
        int sy = y + RR - kdy;

        // feat windows: f[c][t] = feat[c0+c, sy, x0-4+t], t in [0,16); OOB -> 0
        float f[CT][16];
        const float* frow = featb + sy * Wn + x0 - RR;
        #pragma unroll
        for (int c = 0; c < CT; ++c) {
            const float* p = frow + (size_t)c * HWn;
            float4 f0 = (tx == 0)       ? make_float4(0,0,0,0) : *reinterpret_cast<const float4*>(p);
            float4 f1 = *reinterpret_cast<const float4*>(p + 4);
            float4 f2 = *reinterpret_cast<const float4*>(p + 8);
            float4 f3 = (tx == NTX - 1) ? make_float4(0,0,0,0) : *reinterpret_cast<const float4*>(p + 12);
            f[c][0]=f0.x;  f[c][1]=f0.y;  f[c][2]=f0.z;  f[c][3]=f0.w;
            f[c][4]=f1.x;  f[c][5]=f1.y;  f[c][6]=f1.z;  f[c][7]=f1.w;
            f[c][8]=f2.x;  f[c][9]=f2.y;  f[c][10]=f2.z; f[c][11]=f2.w;
            f[c][12]=f3.x; f[c][13]=f3.y; f[c][14]=f3.z; f[c][15]=f3.w;
        }

        // cv for output x0+j lives at lds[row][x0+4+j] -> two aligned b128 per row.
        // Depth-1 software prefetch of the NEXT kdx row's pair: the two ds_reads
        // for kdx+1 issue before the 32-FMA block of kdx, hiding ~120cy LDS latency.
        const float4* base = reinterpret_cast<const float4*>(lds) + (tx * 2 + 1) + kdy * DD * LW4;
        float4 ca = base[0];
        float4 cb = base[1];
        #pragma unroll
        for (int kdx = 0; kdx < DD; ++kdx) {
            float4 na = ca, nb = cb;
            if (kdx < DD - 1) {
                na = base[(kdx + 1) * LW4];
                nb = base[(kdx + 1) * LW4 + 1];
            }
            float cv[8] = {ca.x, ca.y, ca.z, ca.w, cb.x, cb.y, cb.z, cb.w};
            #pragma unroll
            for (int c = 0; c < CT; ++c)
                #pragma unroll
                for (int j = 0; j < TXR; ++j)
                    acc[c][j] = fmaf(cv[j], f[c][j + 8 - kdx], acc[c][j]);
            ca = na; cb = nb;
        }
    }

    float* ob = out + ((size_t)b * Cn + c0) * HWn + (size_t)y * Wn + x0;
    #pragma unroll
    for (int c = 0; c < CT; ++c) {
        *reinterpret_cast<float4*>(ob + (size_t)c * HWn)     = make_float4(acc[c][0], acc[c][1], acc[c][2], acc[c][3]);
        *reinterpret_cast<float4*>(ob + (size_t)c * HWn + 4) = make_float4(acc[c][4], acc[c][5], acc[c][6], acc[c][7]);
    }
}

extern "C" void kernel_launch(void* const* d_in, const int* in_sizes, int n_in,
                              void* d_out, int out_size, void* d_ws, size_t ws_size,
                              hipStream_t stream)
{
    const float* corr = (const float*)d_in[0];   // [16,81,96,96]
    const float* feat = (const float*)d_in[1];   // [16,256,96,96]
    float* out = (float*)d_out;                  // [16,256,96,96]

    const int grid = Bn * Hn * NCG;              // 16*96*4 = 6144
    corrT7_kernel<<<grid, NTH, 0, stream>>>(corr, feat, out);
}

// Round 8
// 254.082 us; speedup vs baseline: 14.2263x; 1.0024x over previous
//
#include <hip/hip_runtime.h>

// out[b,c,y,x] = sum_{kdy,kdx in [0,9)} corr[b, kdy*9+kdx, y+4-kdy, x+4-kdx] * feat[b,c, y+4-kdy, x+4-kdx]
// (zero padding outside [0,96) in both spatial dims)

#define RR 4
#define DD 9
#define D2 81
#define Bn 16
#define Cn 256
#define Hn 96
#define Wn 96
#define HWn (Hn*Wn)

#define NTX 12            // x-lane groups
#define TXR 8             // x outputs per thread
#define NTC 32            // channel lanes
#define CT  2             // channels per thread
#define NCB (NTC*CT)      // 64 channels per block
#define NCG (Cn/NCB)      // 4 channel groups
#define NTH (NTX*NTC)     // 384 threads
#define LW  100           // padded LDS row width (floats): cols 0..3 zero pad, 4..99 data; 81*100*4 = 32400 B -> 5 blocks/CU
#define LW4 (LW/4)        // 25 float4 per row

__global__ __launch_bounds__(NTH, 6)
void corrT8_kernel(const float* __restrict__ corr,
                   const float* __restrict__ feat,
                   float* __restrict__ out)
{
    __shared__ float lds[D2 * LW];          // 32400 B

    // XCD-chunked bijective swizzle (grid 6144 % 8 == 0)
    int bid = blockIdx.x;
    int sw  = (bid & 7) * (gridDim.x >> 3) + (bid >> 3);
    int cg  = sw & (NCG - 1);               // channel-group fastest: corr L2 reuse
    int y   = (sw >> 2) % Hn;
    int b   = sw / (NCG * Hn);

    const int tid = threadIdx.x;
    const float* corrb = corr + (size_t)b * D2 * HWn;

    // ---- stage corr rows into LDS, x-shifted by kdx, zero-padded ----
    // lds[row][col] = corr[b, row, y+4-kdy, col - kdx]  (0 if OOB), row = kdy*9+kdx
    for (int idx = tid; idx < D2 * LW4; idx += NTH) {
        int row = idx / LW4;
        int c4  = idx - row * LW4;
        int kdy = row / DD;
        int kdx = row - kdy * DD;
        int sy  = y + RR - kdy;
        float4 v = make_float4(0.f, 0.f, 0.f, 0.f);
        if (sy >= 0 && sy < Hn) {
            const float* src = corrb + (size_t)row * HWn + sy * Wn;
            int col0 = c4 * 4;
            #pragma unroll
            for (int e = 0; e < 4; ++e) {
                int sx = col0 + e - kdx;
                if (sx >= 0 && sx < Wn) (&v.x)[e] = src[sx];
            }
        }
        *reinterpret_cast<float4*>(&lds[row * LW + c4 * 4]) = v;
    }
    __syncthreads();

    const int tx = tid % NTX;
    const int tc = tid / NTX;
    const int x0 = tx * TXR;
    const int c0 = cg * NCB + tc * CT;

    const float* featb = feat + ((size_t)b * Cn + c0) * HWn;

    float acc[CT][TXR] = {};

    // contiguous valid kdy range: sy = y+4-kdy in [0,96)
    const int klo = max(0, y - (Hn - 1 - RR));
    const int khi = min(DD - 1, y + RR);

    #pragma unroll 1
    for (int kdy = klo; kdy <= khi; ++kdy) {
        int sy = y + RR - kdy;

        // feat windows: f[c][t] = feat[c0+c, sy, x0-4+t], t in [0,16); OOB -> 0
        float f[CT][16];
        const float* frow = featb + sy * Wn + x0 - RR;
        #pragma unroll
        for (int c = 0; c < CT; ++c) {
            const float* p = frow + (size_t)c * HWn;
            float4 f0 = (tx == 0)       ? make_float4(0,0,0,0) : *reinterpret_cast<const float4*>(p);
            float4 f1 = *reinterpret_cast<const float4*>(p + 4);
            float4 f2 = *reinterpret_cast<const float4*>(p + 8);
            float4 f3 = (tx == NTX - 1) ? make_float4(0,0,0,0) : *reinterpret_cast<const float4*>(p + 12);
            f[c][0]=f0.x;  f[c][1]=f0.y;  f[c][2]=f0.z;  f[c][3]=f0.w;
            f[c][4]=f1.x;  f[c][5]=f1.y;  f[c][6]=f1.z;  f[c][7]=f1.w;
            f[c][8]=f2.x;  f[c][9]=f2.y;  f[c][10]=f2.z; f[c][11]=f2.w;
            f[c][12]=f3.x; f[c][13]=f3.y; f[c][14]=f3.z; f[c][15]=f3.w;
        }

        // cv for output x0+j lives at lds[row][x0+4+j] -> two aligned b128 per row.
        // Depth-1 prefetch of next kdx row's pair hides LDS latency under the FMA block.
        const float4* base = reinterpret_cast<const float4*>(lds) + (tx * 2 + 1) + kdy * DD * LW4;
        float4 ca = base[0];
        float4 cb = base[1];
        #pragma unroll
        for (int kdx = 0; kdx < DD; ++kdx) {
            float4 na = ca, nb = cb;
            if (kdx < DD - 1) {
                na = base[(kdx + 1) * LW4];
                nb = base[(kdx + 1) * LW4 + 1];
            }
            float cv[8] = {ca.x, ca.y, ca.z, ca.w, cb.x, cb.y, cb.z, cb.w};
            #pragma unroll
            for (int c = 0; c < CT; ++c)
                #pragma unroll
                for (int j = 0; j < TXR; ++j)
                    acc[c][j] = fmaf(cv[j], f[c][j + 8 - kdx], acc[c][j]);
            ca = na; cb = nb;
        }
    }

    float* ob = out + ((size_t)b * Cn + c0) * HWn + (size_t)y * Wn + x0;
    #pragma unroll
    for (int c = 0; c < CT; ++c) {
        *reinterpret_cast<float4*>(ob + (size_t)c * HWn)     = make_float4(acc[c][0], acc[c][1], acc[c][2], acc[c][3]);
        *reinterpret_cast<float4*>(ob + (size_t)c * HWn + 4) = make_float4(acc[c][4], acc[c][5], acc[c][6], acc[c][7]);
    }
}

extern "C" void kernel_launch(void* const* d_in, const int* in_sizes, int n_in,
                              void* d_out, int out_size, void* d_ws, size_t ws_size,
                              hipStream_t stream)
{
    const float* corr = (const float*)d_in[0];   // [16,81,96,96]
    const float* feat = (const float*)d_in[1];   // [16,256,96,96]
    float* out = (float*)d_out;                  // [16,256,96,96]

    const int grid = Bn * Hn * NCG;              // 16*96*4 = 6144
    corrT8_kernel<<<grid, NTH, 0, stream>>>(corr, feat, out);
}